// Round 6
// baseline (1660.028 us; speedup 1.0000x reference)
//
#include <hip/hip_runtime.h>
#include <hip/hip_fp16.h>
#include <cstddef>

#define NROWS 16384
#define NE    8192
#define DD    256

typedef unsigned long long u64;
typedef float vf4 __attribute__((ext_vector_type(4)));
typedef short bf16x8 __attribute__((ext_vector_type(8)));
typedef float f32x4 __attribute__((ext_vector_type(4)));
typedef unsigned short us8 __attribute__((ext_vector_type(8)));

#define OH_TOT ((size_t)NROWS * NE)           // 134217728 floats
#define OH_VEC ((OH_TOT - 4) / 4)             // 33554431 aligned vf4 slots
#define CANDOFF 70000000                      // float offset of cand list in onehot region
#define CAND_CAP 60000000

// ---------------------------------------------------------------------------
// k_rowsq: zsq[n] = sum(z[n,:]^2) (numpy pairwise order, bit-exact), esq
// likewise for emb. ALSO: Ssum[n] = sum(|z[n,:]|) (any order; used only in a
// rigorous error bound, slack included in the 1e-6 constant), best[] init,
// counts=0, cand_n=0.
// ---------------------------------------------------------------------------
__global__ __launch_bounds__(256) void k_rowsq(
    const float* __restrict__ z, const float* __restrict__ emb,
    float* __restrict__ zsq, float* __restrict__ esq,
    u64* __restrict__ best, int* __restrict__ counts,
    float* __restrict__ Ssum, int* __restrict__ cand_n)
{
  const int g = blockIdx.x * 256 + threadIdx.x;   // 0 .. 24575
  if (g == 0) *cand_n = 0;
  if (g < NE) counts[g] = 0;
  if (g < NROWS) best[g] = ~0ull;

  const float* row;
  float* outp;
  if (g < NROWS) { row = z + (size_t)g * DD;            outp = zsq + g; }
  else           { row = emb + (size_t)(g - NROWS) * DD; outp = esq + (g - NROWS); }

  float sa = 0.0f;   // abs-sum (no ordering constraint)
  float half_s[2];
#pragma unroll
  for (int h = 0; h < 2; ++h) {
    const float* p = row + h * 128;
    float r[8];
    {
      const float4 v0 = *(const float4*)(p);
      const float4 v1 = *(const float4*)(p + 4);
      const float xs[8] = {v0.x, v0.y, v0.z, v0.w, v1.x, v1.y, v1.z, v1.w};
#pragma unroll
      for (int j = 0; j < 8; ++j) {
        float sq = xs[j] * xs[j];
        asm volatile("" : "+v"(sq));   // block FMA contraction: np rounds x*x first
        r[j] = sq;
        sa += fabsf(xs[j]);
      }
    }
    for (int i = 8; i < 128; i += 8) {
      const float4 v0 = *(const float4*)(p + i);
      const float4 v1 = *(const float4*)(p + i + 4);
      const float xs[8] = {v0.x, v0.y, v0.z, v0.w, v1.x, v1.y, v1.z, v1.w};
#pragma unroll
      for (int j = 0; j < 8; ++j) {
        float sq = xs[j] * xs[j];
        asm volatile("" : "+v"(sq));
        r[j] = r[j] + sq;
        sa += fabsf(xs[j]);
      }
    }
    half_s[h] = ((r[0] + r[1]) + (r[2] + r[3])) + ((r[4] + r[5]) + (r[6] + r[7]));
  }
  *outp = half_s[0] + half_s[1];
  if (g < NROWS) Ssum[g] = sa;
}

// ---------------------------------------------------------------------------
// f2bf_rne: fp32 -> bf16 round-to-nearest-even (bit-exact, mode-independent;
// the screen's error bound uses u=2^-8 so even truncation would be covered).
// ---------------------------------------------------------------------------
__device__ __forceinline__ unsigned short f2bf_rne(float f) {
  const unsigned u = __float_as_uint(f);
  return (unsigned short)((u + 0x7FFFu + ((u >> 16) & 1u)) >> 16);
}

// ---------------------------------------------------------------------------
// k_gemm: bf16 MFMA screening GEMM. r[row][col] = fp16(fl(esq[col] -
// 2*dot_bf16)) written into the one-hot output region (reused as scratch;
// zero-filled later by k_zero). 128x128 tile, 4 waves, each wave 64x64 via
// 4x4 mfma_f32_16x16x32_bf16 frags, K staged in 32-chunks, double-buffered.
// Fragment mappings per the m89-verified gfx950 layout:
//   A/B: lane&15 = row/col, k = (lane>>4)*8 + elem (k-permutation cancels
//   between A and B as long as both load identically).
//   C/D: col = lane&15, row = (lane>>4)*4 + reg.
// ---------------------------------------------------------------------------
__global__ __launch_bounds__(256) void k_gemm(
    const float* __restrict__ z, const float* __restrict__ emb,
    const float* __restrict__ esq, unsigned short* __restrict__ rplane)
{
  __shared__ unsigned short As[2][128][40];   // 32 k + 8 pad halfs (80 B rows)
  __shared__ unsigned short Bs[2][128][40];

  const int tid = threadIdx.x;
  const int lane = tid & 63;
  const int wave = tid >> 6;
  const int R0 = blockIdx.x * 128;
  const int C0 = blockIdx.y * 128;
  const int sr = tid >> 1;        // staged row 0..127
  const int sh = tid & 1;         // k-half (16 floats)
  const float* za = z + (size_t)(R0 + sr) * DD + sh * 16;
  const float* ea = emb + (size_t)(C0 + sr) * DD + sh * 16;
  const int wr = (wave >> 1) * 64;
  const int wc = (wave & 1) * 64;
  const int l15 = lane & 15;
  const int kg = lane >> 4;       // 0..3

  f32x4 acc[4][4];
#pragma unroll
  for (int i = 0; i < 4; ++i)
#pragma unroll
    for (int j = 0; j < 4; ++j) acc[i][j] = (f32x4){0.0f, 0.0f, 0.0f, 0.0f};

#define GSTAGE(B_, K0_)                                                    \
  {                                                                        \
    const float4 a0 = *(const float4*)(za + (K0_));                        \
    const float4 a1 = *(const float4*)(za + (K0_) + 4);                    \
    const float4 a2 = *(const float4*)(za + (K0_) + 8);                    \
    const float4 a3 = *(const float4*)(za + (K0_) + 12);                   \
    const float4 b0 = *(const float4*)(ea + (K0_));                        \
    const float4 b1 = *(const float4*)(ea + (K0_) + 4);                    \
    const float4 b2 = *(const float4*)(ea + (K0_) + 8);                    \
    const float4 b3 = *(const float4*)(ea + (K0_) + 12);                   \
    us8 w0, w1, x0, x1;                                                    \
    w0[0] = f2bf_rne(a0.x); w0[1] = f2bf_rne(a0.y);                        \
    w0[2] = f2bf_rne(a0.z); w0[3] = f2bf_rne(a0.w);                        \
    w0[4] = f2bf_rne(a1.x); w0[5] = f2bf_rne(a1.y);                        \
    w0[6] = f2bf_rne(a1.z); w0[7] = f2bf_rne(a1.w);                        \
    w1[0] = f2bf_rne(a2.x); w1[1] = f2bf_rne(a2.y);                        \
    w1[2] = f2bf_rne(a2.z); w1[3] = f2bf_rne(a2.w);                        \
    w1[4] = f2bf_rne(a3.x); w1[5] = f2bf_rne(a3.y);                        \
    w1[6] = f2bf_rne(a3.z); w1[7] = f2bf_rne(a3.w);                        \
    x0[0] = f2bf_rne(b0.x); x0[1] = f2bf_rne(b0.y);                        \
    x0[2] = f2bf_rne(b0.z); x0[3] = f2bf_rne(b0.w);                        \
    x0[4] = f2bf_rne(b1.x); x0[5] = f2bf_rne(b1.y);                        \
    x0[6] = f2bf_rne(b1.z); x0[7] = f2bf_rne(b1.w);                        \
    x1[0] = f2bf_rne(b2.x); x1[1] = f2bf_rne(b2.y);                        \
    x1[2] = f2bf_rne(b2.z); x1[3] = f2bf_rne(b2.w);                        \
    x1[4] = f2bf_rne(b3.x); x1[5] = f2bf_rne(b3.y);                        \
    x1[6] = f2bf_rne(b3.z); x1[7] = f2bf_rne(b3.w);                        \
    *(us8*)&As[B_][sr][sh * 16]     = w0;                                  \
    *(us8*)&As[B_][sr][sh * 16 + 8] = w1;                                  \
    *(us8*)&Bs[B_][sr][sh * 16]     = x0;                                  \
    *(us8*)&Bs[B_][sr][sh * 16 + 8] = x1;                                  \
  }

#define GCOMP(B_)                                                          \
  {                                                                        \
    bf16x8 af[4], bf[4];                                                   \
    _Pragma("unroll")                                                      \
    for (int q = 0; q < 4; ++q) {                                          \
      af[q] = *(const bf16x8*)&As[B_][wr + q * 16 + l15][kg * 8];          \
      bf[q] = *(const bf16x8*)&Bs[B_][wc + q * 16 + l15][kg * 8];          \
    }                                                                      \
    _Pragma("unroll")                                                      \
    for (int i = 0; i < 4; ++i)                                            \
      _Pragma("unroll")                                                    \
      for (int j = 0; j < 4; ++j)                                          \
        acc[i][j] = __builtin_amdgcn_mfma_f32_16x16x32_bf16(               \
            af[i], bf[j], acc[i][j], 0, 0, 0);                             \
  }

  GSTAGE(0, 0);
  __syncthreads();
  for (int kt = 0; kt < 8; ++kt) {
    if (kt + 1 < 8) GSTAGE((kt + 1) & 1, (kt + 1) * 32);
    GCOMP(kt & 1);
    __syncthreads();
  }

  // epilogue: r = fp16(fl(esq - 2*acc)) -> rplane
  float ev[4];
#pragma unroll
  for (int j = 0; j < 4; ++j) ev[j] = esq[C0 + wc + j * 16 + l15];
#pragma unroll
  for (int i = 0; i < 4; ++i) {
#pragma unroll
    for (int j = 0; j < 4; ++j) {
      const int col = C0 + wc + j * 16 + l15;
#pragma unroll
      for (int r = 0; r < 4; ++r) {
        const int row = R0 + wr + i * 16 + kg * 4 + r;
        const float rv = ev[j] - 2.0f * acc[i][j][r];
        rplane[(size_t)row * NE + col] = __half_as_ushort(__float2half_rn(rv));
      }
    }
  }
}

// ---------------------------------------------------------------------------
// k_scan: one wave per row. Finds m = min_c r[row][c], then emits every col
// with r <= m + W as a candidate. W is a RIGOROUS worst-case window:
//   eps_r = 1e-6 * Ssum[row]   (bf16 input rounding u=2^-8 on both operands,
//                               + MFMA fp32-accum, + Ssum slack)
//   mu_r  = (zsq+2)*1.2e-7     (the reference chain's own two fp32 roundings)
//   Q     = (|m|+2e-3)*2^-11   (fp16 storage quantization near the min)
//   W = 2*(mu + 2*eps + Q + 5e-8)
// Any col whose exact-chain d could be <= the winner's satisfies r <= m+W.
// ---------------------------------------------------------------------------
__global__ __launch_bounds__(256) void k_scan(
    const unsigned short* __restrict__ rplane,
    const float* __restrict__ zsq, const float* __restrict__ Ssum,
    unsigned* __restrict__ cand, int* __restrict__ cand_n)
{
  const int row = blockIdx.x * 4 + (threadIdx.x >> 6);
  const int lane = threadIdx.x & 63;
  const us8* src = (const us8*)(rplane + (size_t)row * NE) + lane;
  us8 v[16];
#pragma unroll
  for (int c = 0; c < 16; ++c) v[c] = src[c * 64];

  float m = 1e30f;
#pragma unroll
  for (int c = 0; c < 16; ++c)
#pragma unroll
    for (int j = 0; j < 8; ++j)
      m = fminf(m, __half2float(__ushort_as_half(v[c][j])));
#pragma unroll
  for (int off = 1; off < 64; off <<= 1)
    m = fminf(m, __shfl_xor(m, off, 64));

  const float eps = 1.0e-6f * Ssum[row];
  const float mu  = (zsq[row] + 2.0f) * 1.2e-7f;
  const float Q   = (fabsf(m) + 2.0e-3f) * 4.8828125e-4f;
  const float thr = m + 2.0f * (mu + 2.0f * eps + Q + 5.0e-8f);

#pragma unroll
  for (int c = 0; c < 16; ++c) {
#pragma unroll
    for (int j = 0; j < 8; ++j) {
      const float f = __half2float(__ushort_as_half(v[c][j]));
      if (f <= thr) {
        const int slot = atomicAdd(cand_n, 1);
        if (slot < CAND_CAP)
          cand[slot] = ((unsigned)row << 13) | (unsigned)(c * 512 + lane * 8 + j);
      }
    }
  }
}

// ---------------------------------------------------------------------------
// k_recheck: exact fp32 chain (ascending-k fmaf, identical rounding to the
// reference / previous passing kernel) for each candidate; u64-packed
// atomicMin gives exact argmin with np.argmin first-index tie-break.
// ---------------------------------------------------------------------------
__global__ __launch_bounds__(256) void k_recheck(
    const float* __restrict__ z, const float* __restrict__ emb,
    const float* __restrict__ zsq, const float* __restrict__ esq,
    const unsigned* __restrict__ cand, const int* __restrict__ cand_n,
    u64* __restrict__ best)
{
  const int n = min(*cand_n, CAND_CAP);
  for (int i = blockIdx.x * 256 + threadIdx.x; i < n; i += gridDim.x * 256) {
    const unsigned e = cand[i];
    const int row = (int)(e >> 13);
    const int col = (int)(e & (NE - 1));
    const float4* zr = (const float4*)(z + (size_t)row * DD);
    const float4* er = (const float4*)(emb + (size_t)col * DD);
    float dot = 0.0f;
#pragma unroll 8
    for (int q = 0; q < 64; ++q) {
      const float4 a = zr[q];
      const float4 b = er[q];
      dot = fmaf(a.x, b.x, dot);
      dot = fmaf(a.y, b.y, dot);
      dot = fmaf(a.z, b.z, dot);
      dot = fmaf(a.w, b.w, dot);
    }
    const float s1 = zsq[row] + esq[col];
    const float dv = s1 - 2.0f * dot;
    atomicMin(&best[row], ((u64)__float_as_uint(dv) << 32) | (unsigned)col);
  }
}

// ---------------------------------------------------------------------------
// k_zero: zero-fill the one-hot region (it held the r-plane + cand list).
// ---------------------------------------------------------------------------
__global__ __launch_bounds__(256) void k_zero(float* __restrict__ ohbase)
{
  const vf4 zz = {0.0f, 0.0f, 0.0f, 0.0f};
  float* zp = ohbase + 2;                        // 16B-aligned
  size_t s = (size_t)blockIdx.x * 16384 + threadIdx.x;
#pragma unroll 4
  for (int it = 0; it < 64; ++it) {
    if (s < OH_VEC) __builtin_nontemporal_store(zz, (vf4*)(zp + 4 * s));
    s += 256;
  }
  if (blockIdx.x == 0 && threadIdx.x == 0) {
    ohbase[0] = 0.0f; ohbase[1] = 0.0f;
    ohbase[OH_TOT - 2] = 0.0f; ohbase[OH_TOT - 1] = 0.0f;
  }
}

// ---------------------------------------------------------------------------
// k_gather2: 4 rows per block. z_q gather, one-hot 1.0 scatter (zeros laid
// down by k_zero), float(index), counts, per-block loss partial.
// ---------------------------------------------------------------------------
__global__ __launch_bounds__(256) void k_gather2(
    const float* __restrict__ z, const float* __restrict__ emb,
    const u64* __restrict__ best,
    float* __restrict__ out_zq, float* __restrict__ out_onehot,
    float* __restrict__ out_idx, float* __restrict__ partials,
    int* __restrict__ counts)
{
  __shared__ float sred[256];
  const int row = blockIdx.x * 4 + (threadIdx.x >> 6);
  const int lane = threadIdx.x & 63;
  const int idx = (int)(unsigned)(best[row] & 0xffffffffull);
  const int k0 = lane * 4;

  const float4 e  = *(const float4*)(emb + (size_t)idx * DD + k0);
  const float4 zv = *(const float4*)(z + (size_t)row * DD + k0);
  *(float4*)(out_zq + (size_t)row * DD + k0) = e;

  const float dx = e.x - zv.x, dy = e.y - zv.y, dz = e.z - zv.z, dw = e.w - zv.w;
  sred[threadIdx.x] = dx * dx + dy * dy + dz * dz + dw * dw;

  if (lane == 0) {
    out_idx[row] = (float)idx;
    out_onehot[(size_t)row * NE + idx] = 1.0f;
    atomicAdd(&counts[idx], 1);
  }
  __syncthreads();
  for (int s = 128; s > 0; s >>= 1) {
    if (threadIdx.x < s) sred[threadIdx.x] += sred[threadIdx.x + s];
    __syncthreads();
  }
  if (threadIdx.x == 0) partials[blockIdx.x] = sred[0];
}

// ---------------------------------------------------------------------------
// k_final: loss = 1.25 * sum(partials) / (N*D); perplexity from counts.
// ---------------------------------------------------------------------------
__global__ __launch_bounds__(256) void k_final(
    const int* __restrict__ counts, const float* __restrict__ partials,
    float* __restrict__ out_loss, float* __restrict__ out_perp)
{
  __shared__ float sred[256];
  __shared__ float sl[256];
  float le = 0.0f;
  for (int e = threadIdx.x; e < NE; e += 256) {
    const float p = (float)counts[e] * (1.0f / 16384.0f);
    le += p * logf(p + 1e-10f);
  }
  float ll = 0.0f;
  for (int b = threadIdx.x; b < NROWS / 4; b += 256) ll += partials[b];
  sred[threadIdx.x] = le;
  sl[threadIdx.x] = ll;
  __syncthreads();
  for (int s = 128; s > 0; s >>= 1) {
    if (threadIdx.x < s) {
      sred[threadIdx.x] += sred[threadIdx.x + s];
      sl[threadIdx.x] += sl[threadIdx.x + s];
    }
    __syncthreads();
  }
  if (threadIdx.x == 0) {
    *out_perp = expf(-sred[0]);
    *out_loss = sl[0] * (1.25f / 4194304.0f);  // (1+beta) * sum / (N*D)
  }
}

// ---------------------------------------------------------------------------
// Output layout (float32, concatenated in reference return order):
//   [0]                loss                       (1)
//   [1 .. 4194304]     z_q_st                     (16384*256)
//   [4194305]          perplexity                 (1)
//   [4194306 ..]       min_encodings one-hot      (16384*8192)
//   [138412034 ..]     min_encoding_indices       (16384, written as float)
// The one-hot region doubles as scratch before k_zero:
//   halfs  [base+8B .. +268MB)   r-plane (fp16 screen values)
//   u32s   [base+280MB ..)       candidate list
// ---------------------------------------------------------------------------
extern "C" void kernel_launch(void* const* d_in, const int* in_sizes, int n_in,
                              void* d_out, int out_size, void* d_ws, size_t ws_size,
                              hipStream_t stream) {
  const float* z   = (const float*)d_in[0];
  const float* emb = (const float*)d_in[1];

  float* out        = (float*)d_out;
  float* out_loss   = out;
  float* out_zq     = out + 1;
  float* out_perp   = out + 4194305;
  float* out_onehot = out + 4194306;
  float* out_idx    = out + 138412034;

  float* zsq      = (float*)d_ws;            // 16384 f
  float* esq      = zsq + NROWS;             // 8192 f
  u64*   best     = (u64*)(esq + NE);        // 16384 u64 (8B-aligned: offset 96 KB)
  int*   counts   = (int*)(best + NROWS);    // 8192 int
  float* partials = (float*)(counts + NE);   // 4096 f
  float* Ssum     = partials + 4096;         // 16384 f
  int*   cand_n   = (int*)(Ssum + NROWS);    // 1 int

  unsigned short* rplane = (unsigned short*)(out_onehot + 2);   // 16B-aligned
  unsigned* cand = (unsigned*)(out_onehot + CANDOFF);

  k_rowsq<<<96, 256, 0, stream>>>(z, emb, zsq, esq, best, counts, Ssum, cand_n);
  k_gemm<<<dim3(NROWS / 128, NE / 128), 256, 0, stream>>>(z, emb, esq, rplane);
  k_scan<<<NROWS / 4, 256, 0, stream>>>(rplane, zsq, Ssum, cand, cand_n);
  k_recheck<<<512, 256, 0, stream>>>(z, emb, zsq, esq, cand, cand_n, best);
  k_zero<<<2048, 256, 0, stream>>>(out_onehot);
  k_gather2<<<NROWS / 4, 256, 0, stream>>>(z, emb, best, out_zq, out_onehot,
                                           out_idx, partials, counts);
  k_final<<<1, 256, 0, stream>>>(counts, partials, out_loss, out_perp);
}

// Round 7
// 908.401 us; speedup vs baseline: 1.8274x; 1.8274x over previous
//
#include <hip/hip_runtime.h>
#include <cstddef>

#define NROWS 16384
#define NE    8192
#define DD    256

typedef unsigned long long u64;
typedef float vf4 __attribute__((ext_vector_type(4)));
typedef short bf16x8 __attribute__((ext_vector_type(8)));
typedef float f32x4 __attribute__((ext_vector_type(4)));
typedef unsigned short us8 __attribute__((ext_vector_type(8)));

#define OH_TOT ((size_t)NROWS * NE)           // 134217728 floats
#define OH_VEC ((OH_TOT - 4) / 4)             // 33554431 aligned vf4 slots
#define CAND_CAP 4000000                      // u32 entries in out_zq region (16 MB)
#define LLIST_CAP 2048

// ---------------------------------------------------------------------------
// k_rowsq: zsq[n] = sum(z[n,:]^2) in numpy pairwise order (bit-exact), esq
// likewise. wadd[n] = full per-row screen window (rigorous worst-case):
//   eps = 1e-6*Ssum (bf16 RNE 2^-8 on both operands: 9.6e-7*Ssum worst-case)
//   mu  = (zsq+2)*1.2e-7 (ref chain's two fp32 roundings at ~256 scale)
//   wadd = 2*(mu + 2*eps + 5e-8)       (validated by round-6 pass)
// Also inits best[], counts, cand_n.
// ---------------------------------------------------------------------------
__global__ __launch_bounds__(256) void k_rowsq(
    const float* __restrict__ z, const float* __restrict__ emb,
    float* __restrict__ zsq, float* __restrict__ esq,
    u64* __restrict__ best, int* __restrict__ counts,
    float* __restrict__ wadd, int* __restrict__ cand_n)
{
  const int g = blockIdx.x * 256 + threadIdx.x;   // 0 .. 24575
  if (g == 0) *cand_n = 0;
  if (g < NE) counts[g] = 0;
  if (g < NROWS) best[g] = ~0ull;

  const float* row;
  float* outp;
  if (g < NROWS) { row = z + (size_t)g * DD;            outp = zsq + g; }
  else           { row = emb + (size_t)(g - NROWS) * DD; outp = esq + (g - NROWS); }

  float sa = 0.0f;
  float half_s[2];
#pragma unroll
  for (int h = 0; h < 2; ++h) {
    const float* p = row + h * 128;
    float r[8];
    {
      const float4 v0 = *(const float4*)(p);
      const float4 v1 = *(const float4*)(p + 4);
      const float xs[8] = {v0.x, v0.y, v0.z, v0.w, v1.x, v1.y, v1.z, v1.w};
#pragma unroll
      for (int j = 0; j < 8; ++j) {
        float sq = xs[j] * xs[j];
        asm volatile("" : "+v"(sq));   // np rounds x*x before the add chain
        r[j] = sq;
        sa += fabsf(xs[j]);
      }
    }
    for (int i = 8; i < 128; i += 8) {
      const float4 v0 = *(const float4*)(p + i);
      const float4 v1 = *(const float4*)(p + i + 4);
      const float xs[8] = {v0.x, v0.y, v0.z, v0.w, v1.x, v1.y, v1.z, v1.w};
#pragma unroll
      for (int j = 0; j < 8; ++j) {
        float sq = xs[j] * xs[j];
        asm volatile("" : "+v"(sq));
        r[j] = r[j] + sq;
        sa += fabsf(xs[j]);
      }
    }
    half_s[h] = ((r[0] + r[1]) + (r[2] + r[3])) + ((r[4] + r[5]) + (r[6] + r[7]));
  }
  const float zs = half_s[0] + half_s[1];
  *outp = zs;
  if (g < NROWS)
    wadd[g] = 2.0f * ((zs + 2.0f) * 1.2e-7f + 2.0f * (1.0e-6f * sa) + 5.0e-8f);
}

__device__ __forceinline__ unsigned short f2bf_rne(float f) {
  const unsigned u = __float_as_uint(f);
  return (unsigned short)((u + 0x7FFFu + ((u >> 16) & 1u)) >> 16);
}
// orderable-uint encoding of float (monotone): handles negatives
__device__ __forceinline__ unsigned encf(float f) {
  const unsigned u = __float_as_uint(f);
  return (u & 0x80000000u) ? ~u : (u | 0x80000000u);
}
__device__ __forceinline__ float decf(unsigned k) {
  const unsigned u = (k & 0x80000000u) ? (k ^ 0x80000000u) : ~k;
  return __uint_as_float(u);
}

// ---------------------------------------------------------------------------
// k_screen: fused bf16-MFMA screen + block-local running-min + candidate
// emission + one-hot zero-fill. 256 blocks (128 row-panels x 2 col-halves,
// XCD-decoded so each XCD touches one emb half), 512 threads = 8 waves
// (2 row x 4 col), 1 block/CU. z A-frags persistent in regs (128 VGPR);
// emb tiles (128 cols x 256 k bf16) double-buffered in LDS with XOR chunk
// swizzle. Emission threshold = LDS running min + wadd (conservative:
// running min >= final min always -> superset of true candidate set; the
// exact argmin col always qualifies). Candidates -> LDS list -> one flush
// into the out_zq region (overwritten later by k_gather2).
// ---------------------------------------------------------------------------
__global__ __launch_bounds__(512, 2) void k_screen(
    const float* __restrict__ z, const float* __restrict__ emb,
    const float* __restrict__ esq, const float* __restrict__ wadd,
    unsigned* __restrict__ cand, int* __restrict__ cand_n,
    float* __restrict__ ohbase)
{
  __shared__ unsigned short Bs[2][128][256];   // 128 KB
  __shared__ unsigned smin[128];               // encoded running min per row
  __shared__ float wl[128];                    // per-row window
  __shared__ unsigned llist[LLIST_CAP];        // 8 KB candidate staging
  __shared__ unsigned lcnt;
  __shared__ unsigned gbase;

  const int tid = threadIdx.x;
  const int b = blockIdx.x;                    // 0..255
  const int x = b & 7, q = b >> 3;
  const int half = x & 1;
  const int panel = q * 4 + (x >> 1);          // bijective (m204-style)
  const int R0 = panel * 128;
  const int C0 = half * 4096;

  const int wave = tid >> 6;
  const int lane = tid & 63;
  const int l15 = lane & 15;
  const int kg = lane >> 4;                    // 0..3
  const int wr = (wave >> 2) * 64;             // row half
  const int wc = (wave & 3) * 32;              // col quarter
  const int cb0 = wc + l15;                    // local cols
  const int cb1 = cb0 + 16;

  const int c_st = tid >> 2;                   // staging col 0..127
  const int kq = tid & 3;                      // staging k-quarter
  const int swz = c_st & 7;

  if (tid < 128) { smin[tid] = 0xFFFFFFFFu; wl[tid] = wadd[R0 + tid]; }
  if (tid == 0) lcnt = 0;

  // one-hot zero-fill state: block owns 131072 vf4 slots
  float* zp0 = ohbase + 2;
  size_t zt = (size_t)b * 131072 + tid;
  const vf4 zzero = {0.0f, 0.0f, 0.0f, 0.0f};
  if (b == 0 && tid == 0) { ohbase[0] = 0.0f; ohbase[1] = 0.0f; }
  if (b == 255 && tid == 0) { ohbase[OH_TOT - 2] = 0.0f; ohbase[OH_TOT - 1] = 0.0f; }

  // ---- persistent A-frags: rows R0+wr+i*16+l15, k = kt*32+kg*8 ----
  bf16x8 af[4][8];
#pragma unroll
  for (int i = 0; i < 4; ++i) {
    const float* zp_ = z + (size_t)(R0 + wr + i * 16 + l15) * DD + kg * 8;
#pragma unroll
    for (int kt = 0; kt < 8; ++kt) {
      const float4 a0 = *(const float4*)(zp_ + kt * 32);
      const float4 a1 = *(const float4*)(zp_ + kt * 32 + 4);
      bf16x8 w;
      w[0] = (short)f2bf_rne(a0.x); w[1] = (short)f2bf_rne(a0.y);
      w[2] = (short)f2bf_rne(a0.z); w[3] = (short)f2bf_rne(a0.w);
      w[4] = (short)f2bf_rne(a1.x); w[5] = (short)f2bf_rne(a1.y);
      w[6] = (short)f2bf_rne(a1.z); w[7] = (short)f2bf_rne(a1.w);
      af[i][kt] = w;
    }
  }

  float runmin[16];
#pragma unroll
  for (int i = 0; i < 16; ++i) runmin[i] = 1e30f;

#define SSTAGE(BUF_, TT_)                                                   \
  {                                                                         \
    const float* ep = emb + (size_t)(C0 + (TT_) * 128 + c_st) * DD + kq * 64;\
    unsigned short* dst = &Bs[BUF_][c_st][0];                               \
    _Pragma("unroll")                                                       \
    for (int s = 0; s < 4; ++s) {                                           \
      const float4 f0 = *(const float4*)(ep + 16 * s);                      \
      const float4 f1 = *(const float4*)(ep + 16 * s + 4);                  \
      const float4 f2 = *(const float4*)(ep + 16 * s + 8);                  \
      const float4 f3 = *(const float4*)(ep + 16 * s + 12);                 \
      us8 u0, u1;                                                           \
      u0[0] = f2bf_rne(f0.x); u0[1] = f2bf_rne(f0.y);                       \
      u0[2] = f2bf_rne(f0.z); u0[3] = f2bf_rne(f0.w);                       \
      u0[4] = f2bf_rne(f1.x); u0[5] = f2bf_rne(f1.y);                       \
      u0[6] = f2bf_rne(f1.z); u0[7] = f2bf_rne(f1.w);                       \
      u1[0] = f2bf_rne(f2.x); u1[1] = f2bf_rne(f2.y);                       \
      u1[2] = f2bf_rne(f2.z); u1[3] = f2bf_rne(f2.w);                       \
      u1[4] = f2bf_rne(f3.x); u1[5] = f2bf_rne(f3.y);                       \
      u1[6] = f2bf_rne(f3.z); u1[7] = f2bf_rne(f3.w);                       \
      const int ch0 = (kq * 8 + 2 * s) ^ swz;                               \
      const int ch1 = (kq * 8 + 2 * s + 1) ^ swz;                           \
      *(us8*)(dst + ch0 * 8) = u0;                                          \
      *(us8*)(dst + ch1 * 8) = u1;                                          \
    }                                                                       \
  }

#define PUSH(E_)                                                            \
  {                                                                         \
    const unsigned s_ = atomicAdd(&lcnt, 1u);                               \
    if (s_ < LLIST_CAP) llist[s_] = (E_);                                   \
    else { const int g_ = atomicAdd(cand_n, 1);                             \
           if (g_ < CAND_CAP) cand[g_] = (E_); }                            \
  }

  SSTAGE(0, 0);
  __syncthreads();

  for (int t = 0; t < 32; ++t) {
    const int Cb = C0 + t * 128;
    if (t + 1 < 32) SSTAGE((t + 1) & 1, t + 1);

    // hide one-hot zero stores under the tile
#pragma unroll
    for (int s = 0; s < 8; ++s) {
      if (zt < OH_VEC) __builtin_nontemporal_store(zzero, (vf4*)(zp0 + 4 * zt));
      zt += 512;
    }

    f32x4 acc[4][2];
#pragma unroll
    for (int i = 0; i < 4; ++i) {
      acc[i][0] = (f32x4){0.0f, 0.0f, 0.0f, 0.0f};
      acc[i][1] = (f32x4){0.0f, 0.0f, 0.0f, 0.0f};
    }
    {
      const int bbuf = t & 1;
#pragma unroll
      for (int kt = 0; kt < 8; ++kt) {
        const bf16x8 b0 = *(const bf16x8*)(&Bs[bbuf][cb0][0] + (((kt * 4 + kg) ^ (cb0 & 7)) * 8));
        const bf16x8 b1 = *(const bf16x8*)(&Bs[bbuf][cb1][0] + (((kt * 4 + kg) ^ (cb1 & 7)) * 8));
#pragma unroll
        for (int i = 0; i < 4; ++i) {
          acc[i][0] = __builtin_amdgcn_mfma_f32_16x16x32_bf16(af[i][kt], b0, acc[i][0], 0, 0, 0);
          acc[i][1] = __builtin_amdgcn_mfma_f32_16x16x32_bf16(af[i][kt], b1, acc[i][1], 0, 0, 0);
        }
      }
    }

    const float ev0 = esq[Cb + cb0];
    const float ev1 = esq[Cb + cb1];

    // per-thread running min update (regs only)
#pragma unroll
    for (int i = 0; i < 4; ++i)
#pragma unroll
      for (int r = 0; r < 4; ++r) {
        const float rv0 = ev0 - 2.0f * acc[i][0][r];
        const float rv1 = ev1 - 2.0f * acc[i][1][r];
        runmin[i * 4 + r] = fminf(runmin[i * 4 + r], fminf(rv0, rv1));
      }

    // cross-lane flush to smin on cadence (cheap amortized DS traffic)
    if (t < 4 || (t & 3) == 3) {
#pragma unroll
      for (int i = 0; i < 4; ++i)
#pragma unroll
        for (int r = 0; r < 4; ++r) {
          float mn = runmin[i * 4 + r];
          mn = fminf(mn, __shfl_xor(mn, 1, 16));
          mn = fminf(mn, __shfl_xor(mn, 2, 16));
          mn = fminf(mn, __shfl_xor(mn, 4, 16));
          mn = fminf(mn, __shfl_xor(mn, 8, 16));
          if (l15 == 0) atomicMin(&smin[wr + i * 16 + kg * 4 + r], encf(mn));
        }
    }
    __syncthreads();

    // emission: conservative threshold from current smin
#pragma unroll
    for (int i = 0; i < 4; ++i)
#pragma unroll
      for (int r = 0; r < 4; ++r) {
        const int Rl = wr + i * 16 + kg * 4 + r;
        const float thrf = decf(smin[Rl]) + wl[Rl];
        const float rv0 = ev0 - 2.0f * acc[i][0][r];
        const float rv1 = ev1 - 2.0f * acc[i][1][r];
        if (rv0 <= thrf) PUSH(((unsigned)(R0 + Rl) << 13) | (unsigned)(Cb + cb0));
        if (rv1 <= thrf) PUSH(((unsigned)(R0 + Rl) << 13) | (unsigned)(Cb + cb1));
      }
  }

  __syncthreads();
  const unsigned n = (lcnt < LLIST_CAP) ? lcnt : LLIST_CAP;
  if (tid == 0) gbase = (unsigned)atomicAdd(cand_n, (int)n);
  __syncthreads();
  for (unsigned idx = tid; idx < n; idx += 512) {
    const unsigned g = gbase + idx;
    if (g < CAND_CAP) cand[g] = llist[idx];
  }
}

// ---------------------------------------------------------------------------
// k_recheck: exact fp32 chain (ascending-k fmaf, identical rounding to the
// reference) for each candidate; u64-packed atomicMin -> exact argmin with
// np.argmin first-index tie-break.
// ---------------------------------------------------------------------------
__global__ __launch_bounds__(256) void k_recheck(
    const float* __restrict__ z, const float* __restrict__ emb,
    const float* __restrict__ zsq, const float* __restrict__ esq,
    const unsigned* __restrict__ cand, const int* __restrict__ cand_n,
    u64* __restrict__ best)
{
  const int n = min(*cand_n, CAND_CAP);
  for (int i = blockIdx.x * 256 + threadIdx.x; i < n; i += gridDim.x * 256) {
    const unsigned e = cand[i];
    const int row = (int)(e >> 13);
    const int col = (int)(e & (NE - 1));
    const float4* zr = (const float4*)(z + (size_t)row * DD);
    const float4* er = (const float4*)(emb + (size_t)col * DD);
    float dot = 0.0f;
#pragma unroll 8
    for (int q = 0; q < 64; ++q) {
      const float4 a = zr[q];
      const float4 b = er[q];
      dot = fmaf(a.x, b.x, dot);
      dot = fmaf(a.y, b.y, dot);
      dot = fmaf(a.z, b.z, dot);
      dot = fmaf(a.w, b.w, dot);
    }
    const float s1 = zsq[row] + esq[col];
    const float dv = s1 - 2.0f * dot;
    atomicMin(&best[row], ((u64)__float_as_uint(dv) << 32) | (unsigned)col);
  }
}

// ---------------------------------------------------------------------------
// k_gather2: 4 rows per block. z_q gather (overwrites the cand scratch),
// one-hot 1.0 scatter, float(index), counts, per-block loss partial.
// ---------------------------------------------------------------------------
__global__ __launch_bounds__(256) void k_gather2(
    const float* __restrict__ z, const float* __restrict__ emb,
    const u64* __restrict__ best,
    float* __restrict__ out_zq, float* __restrict__ out_onehot,
    float* __restrict__ out_idx, float* __restrict__ partials,
    int* __restrict__ counts)
{
  __shared__ float sred[256];
  const int row = blockIdx.x * 4 + (threadIdx.x >> 6);
  const int lane = threadIdx.x & 63;
  const int idx = (int)(unsigned)(best[row] & 0xffffffffull);
  const int k0 = lane * 4;

  const float4 e  = *(const float4*)(emb + (size_t)idx * DD + k0);
  const float4 zv = *(const float4*)(z + (size_t)row * DD + k0);
  *(float4*)(out_zq + (size_t)row * DD + k0) = e;

  const float dx = e.x - zv.x, dy = e.y - zv.y, dz = e.z - zv.z, dw = e.w - zv.w;
  sred[threadIdx.x] = dx * dx + dy * dy + dz * dz + dw * dw;

  if (lane == 0) {
    out_idx[row] = (float)idx;
    out_onehot[(size_t)row * NE + idx] = 1.0f;
    atomicAdd(&counts[idx], 1);
  }
  __syncthreads();
  for (int s = 128; s > 0; s >>= 1) {
    if (threadIdx.x < s) sred[threadIdx.x] += sred[threadIdx.x + s];
    __syncthreads();
  }
  if (threadIdx.x == 0) partials[blockIdx.x] = sred[0];
}

// ---------------------------------------------------------------------------
// k_final: loss = 1.25 * sum(partials) / (N*D); perplexity from counts.
// ---------------------------------------------------------------------------
__global__ __launch_bounds__(256) void k_final(
    const int* __restrict__ counts, const float* __restrict__ partials,
    float* __restrict__ out_loss, float* __restrict__ out_perp)
{
  __shared__ float sred[256];
  __shared__ float sl[256];
  float le = 0.0f;
  for (int e = threadIdx.x; e < NE; e += 256) {
    const float p = (float)counts[e] * (1.0f / 16384.0f);
    le += p * logf(p + 1e-10f);
  }
  float ll = 0.0f;
  for (int b = threadIdx.x; b < NROWS / 4; b += 256) ll += partials[b];
  sred[threadIdx.x] = le;
  sl[threadIdx.x] = ll;
  __syncthreads();
  for (int s = 128; s > 0; s >>= 1) {
    if (threadIdx.x < s) {
      sred[threadIdx.x] += sred[threadIdx.x + s];
      sl[threadIdx.x] += sl[threadIdx.x + s];
    }
    __syncthreads();
  }
  if (threadIdx.x == 0) {
    *out_perp = expf(-sred[0]);
    *out_loss = sl[0] * (1.25f / 4194304.0f);  // (1+beta) * sum / (N*D)
  }
}

// ---------------------------------------------------------------------------
// Output layout (float32, reference return order):
//   [0] loss | [1..4194304] z_q_st | [4194305] perplexity
//   [4194306..] one-hot | [138412034..] indices (as float)
// Scratch reuse: cand list (u32) lives in the z_q region until k_gather2
// overwrites it (d_out is fast for writes; only ~MBs are ever READ back).
// ---------------------------------------------------------------------------
extern "C" void kernel_launch(void* const* d_in, const int* in_sizes, int n_in,
                              void* d_out, int out_size, void* d_ws, size_t ws_size,
                              hipStream_t stream) {
  const float* z   = (const float*)d_in[0];
  const float* emb = (const float*)d_in[1];

  float* out        = (float*)d_out;
  float* out_loss   = out;
  float* out_zq     = out + 1;
  float* out_perp   = out + 4194305;
  float* out_onehot = out + 4194306;
  float* out_idx    = out + 138412034;

  float* zsq      = (float*)d_ws;            // 16384 f
  float* esq      = zsq + NROWS;             // 8192 f
  u64*   best     = (u64*)(esq + NE);        // 16384 u64
  int*   counts   = (int*)(best + NROWS);    // 8192 int
  float* partials = (float*)(counts + NE);   // 4096 f
  float* wadd     = partials + 4096;         // 16384 f
  int*   cand_n   = (int*)(wadd + NROWS);    // 1 int

  unsigned* cand = (unsigned*)out_zq;        // scratch until k_gather2

  k_rowsq<<<96, 256, 0, stream>>>(z, emb, zsq, esq, best, counts, wadd, cand_n);
  k_screen<<<256, 512, 0, stream>>>(z, emb, esq, wadd, cand, cand_n, out_onehot);
  k_recheck<<<512, 256, 0, stream>>>(z, emb, zsq, esq, cand, cand_n, best);
  k_gather2<<<NROWS / 4, 256, 0, stream>>>(z, emb, best, out_zq, out_onehot,
                                           out_idx, partials, counts);
  k_final<<<1, 256, 0, stream>>>(counts, partials, out_loss, out_perp);
}